// Round 6
// baseline (1570.094 us; speedup 1.0000x reference)
//
#include <hip/hip_runtime.h>
#include <hip/hip_bf16.h>
#include <math.h>

#define NN 1024
#define BB 64
#define DIN 2
#define HH 64
#define II 66
#define EE 16
#define KMX 7
#define CC (BB*II)   // 4224

typedef __attribute__((ext_vector_type(8))) short short8;   // 8 bf16 (4 VGPRs)
typedef __attribute__((ext_vector_type(4))) float f32x4;

// ---------------- adp softmax (bf16 out) + nv ----------------
__global__ __launch_bounds__(256) void k_adp_nv(
    const float* __restrict__ nv1, const float* __restrict__ nv2,
    const float* __restrict__ w1, const float* __restrict__ b1,
    const float* __restrict__ w2, const float* __restrict__ b2,
    __hip_bfloat16* __restrict__ adp_bf, float* __restrict__ nv)
{
  __shared__ float s_nv1[16];
  __shared__ float logits[1024];
  __shared__ float red[256];
  int n = blockIdx.x, t = threadIdx.x;
  if (t < 16) s_nv1[t] = nv1[n*16+t];
  __syncthreads();
  float lmax = -1e30f;
  for (int m = t; m < 1024; m += 256) {
    float acc = 0.f;
    const float* v2 = nv2 + m*16;
    #pragma unroll
    for (int d = 0; d < 16; ++d) acc += s_nv1[d]*v2[d];
    acc = fmaxf(acc, 0.f);
    logits[m] = acc;
    lmax = fmaxf(lmax, acc);
  }
  red[t] = lmax; __syncthreads();
  for (int s = 128; s > 0; s >>= 1) { if (t < s) red[t] = fmaxf(red[t], red[t+s]); __syncthreads(); }
  float mx = red[0]; __syncthreads();
  float lsum = 0.f;
  for (int m = t; m < 1024; m += 256) { float e = __expf(logits[m]-mx); logits[m] = e; lsum += e; }
  red[t] = lsum; __syncthreads();
  for (int s = 128; s > 0; s >>= 1) { if (t < s) red[t] += red[t+s]; __syncthreads(); }
  float inv = 1.f/red[0];
  for (int m = t; m < 1024; m += 256) adp_bf[n*1024+m] = __float2bfloat16(logits[m]*inv);
  if (t < 16) {
    float a = 0.f, c = 0.f;
    #pragma unroll
    for (int d = 0; d < 16; ++d) a += s_nv1[d]*w1[d*16+t];
    #pragma unroll
    for (int d = 0; d < 16; ++d) c += nv2[n*16+d]*w2[d*16+t];
    a = tanhf(a + b1[t]);
    c = 1.f/(1.f+expf(-(c + b2[t])));
    nv[n*16+t] = a*c;
  }
}

// ---------------- CSR build for sparse supports ----------------
__global__ __launch_bounds__(256) void k_csr(
    const float* __restrict__ s0, const float* __restrict__ s1,
    float* __restrict__ vals, int* __restrict__ cols, int* __restrict__ cnts)
{
  int row = blockIdx.x & 1023;
  int sup = blockIdx.x >> 10;
  const float* S = (sup == 0) ? s0 : s1;
  __shared__ int cnt;
  if (threadIdx.x == 0) cnt = 0;
  __syncthreads();
  int base = (sup*1024 + row)*64;
  for (int m = threadIdx.x; m < 1024; m += 256) {
    float v = S[row*1024+m];
    if (v != 0.f) {
      int idx = atomicAdd(&cnt, 1);
      if (idx < 64) { cols[base+idx] = m; vals[base+idx] = v; }
    }
  }
  __syncthreads();
  if (threadIdx.x == 0) cnts[sup*1024+row] = min(cnt, 64);
}

// ---------------- build x0 into xs slot 0, layout [n][b][i] ----------------
template<int MODE>
__global__ __launch_bounds__(256) void k_x0(
    const float* __restrict__ inputs, const float* __restrict__ state,
    const float* __restrict__ ru, float* __restrict__ xs)
{
  int idx = blockIdx.x*256 + threadIdx.x;       // over N*B*I = 4325376
  int i = idx % II;
  int b = (idx / II) % BB;
  int n = idx / (II*BB);
  float v;
  if (i < DIN) v = inputs[b*(NN*DIN) + n*DIN + i];
  else {
    v = state[b*(NN*HH) + n*HH + (i-DIN)];
    if (MODE == 1) v *= ru[(size_t)(n*BB + b)*128 + (i-DIN)];
  }
  xs[idx] = v;
}

// ---------------- sparse SpMM: Y = S@X  (or 2*S@X - X0), float4 ----------------
template<int P2>
__global__ __launch_bounds__(256) void k_spmm(
    const float* __restrict__ vals, const int* __restrict__ cols, const int* __restrict__ cnts,
    int sup, const float* __restrict__ Xsrc, const float* __restrict__ X0, float* __restrict__ Y)
{
  int n = blockIdx.x;
  __shared__ float sv[64];
  __shared__ int sc[64];
  int cnt = cnts[sup*1024+n];
  if (threadIdx.x < 64 && threadIdx.x < cnt) {
    sv[threadIdx.x] = vals[(sup*1024+n)*64 + threadIdx.x];
    sc[threadIdx.x] = cols[(sup*1024+n)*64 + threadIdx.x] * (CC/4);
  }
  __syncthreads();
  const float4* X4  = (const float4*)Xsrc;
  const float4* X04 = (const float4*)X0;
  float4* Y4 = (float4*)Y;
  for (int c = threadIdx.x; c < CC/4; c += 256) {
    float4 acc = {0.f,0.f,0.f,0.f};
    for (int j = 0; j < cnt; ++j) {
      float s = sv[j];
      float4 x = X4[sc[j] + c];
      acc.x += s*x.x; acc.y += s*x.y; acc.z += s*x.z; acc.w += s*x.w;
    }
    size_t o = (size_t)n*(CC/4) + c;
    if (P2) {
      float4 z = X04[o];
      acc.x = 2.f*acc.x - z.x; acc.y = 2.f*acc.y - z.y;
      acc.z = 2.f*acc.z - z.z; acc.w = 2.f*acc.w - z.w;
    }
    Y4[o] = acc;
  }
}

// ---------------- X [1024][4224] fp32 -> XT [4224][1024] bf16 ----------------
__global__ __launch_bounds__(256) void k_xsplit(
    const float* __restrict__ in, __hip_bfloat16* __restrict__ out)
{
  __shared__ float t[64][65];
  int cb = blockIdx.x*64, kb = blockIdx.y*64;
  int tx = threadIdx.x & 63, ty = threadIdx.x >> 6;   // 64 x 4
  for (int r = ty; r < 64; r += 4) t[r][tx] = in[(size_t)(kb+r)*CC + cb+tx];
  __syncthreads();
  int kp = threadIdx.x & 31, cr0 = threadIdx.x >> 5;  // 32 k-pairs x 8 c-rows
  for (int cr = cr0; cr < 64; cr += 8) {
    __hip_bfloat16 h0 = __float2bfloat16(t[kp*2][cr]);
    __hip_bfloat16 h1 = __float2bfloat16(t[kp*2+1][cr]);
    ushort2 u;
    u.x = *(unsigned short*)&h0;
    u.y = *(unsigned short*)&h1;
    *(ushort2*)&out[(size_t)(cb+cr)*1024 + kb + kp*2] = u;
  }
}

// ---------------- MFMA GEMM: Y[m][c] = adp[m][:]@X[:,c] (opt 2*acc - X0) ----
template<int P2>
__global__ __launch_bounds__(64) void k_gemm_mfma(
    const __hip_bfloat16* __restrict__ A, const __hip_bfloat16* __restrict__ XT,
    const float* __restrict__ X0, float* __restrict__ Y)
{
  int l = threadIdx.x;
  int c0 = blockIdx.x*64, m0 = blockIdx.y*64;
  int lr = l & 15, lg = l >> 4;          // frag row, k-group
  f32x4 acc[4][4] = {};                  // [m-frag][c-frag]
  const short* Ab  = (const short*)A;
  const short* Xb  = (const short*)XT;
  for (int k0 = 0; k0 < 1024; k0 += 32) {
    short8 af[4], bf[4];
    #pragma unroll
    for (int mf = 0; mf < 4; ++mf)
      af[mf] = *(const short8*)&Ab[(size_t)(m0 + mf*16 + lr)*1024 + k0 + lg*8];
    #pragma unroll
    for (int cf = 0; cf < 4; ++cf)
      bf[cf] = *(const short8*)&Xb[(size_t)(c0 + cf*16 + lr)*1024 + k0 + lg*8];
    #pragma unroll
    for (int mf = 0; mf < 4; ++mf)
      #pragma unroll
      for (int cf = 0; cf < 4; ++cf)
        acc[mf][cf] = __builtin_amdgcn_mfma_f32_16x16x32_bf16(af[mf], bf[cf], acc[mf][cf], 0, 0, 0);
  }
  // D map: col = lane&15 (c), row = (lane>>4)*4 + r (m)
  #pragma unroll
  for (int mf = 0; mf < 4; ++mf)
    #pragma unroll
    for (int cf = 0; cf < 4; ++cf)
      #pragma unroll
      for (int r = 0; r < 4; ++r) {
        int m = m0 + mf*16 + lg*4 + r;
        int c = c0 + cf*16 + lr;
        size_t o = (size_t)m*CC + c;
        float v = acc[mf][cf][r];
        Y[o] = P2 ? 2.f*v - X0[o] : v;
      }
}

// ---------------- W pre-gen v2b: register-tiled, conflict-free LDS reads ----
// Thread tile: 4 nodes x 16 elems as 4 chunks of 4 floats at stride 256
// (lane i reads wgc[... + i*4] -> contiguous b128 baseline, no bank conflict).
template<int O>
__global__ __launch_bounds__(256) void k_genw(
    const float* __restrict__ nv, const float* __restrict__ wg,
    float* __restrict__ W, int n0)
{
  constexpr int KIO = KMX*II*O;
  __shared__ float wgc[16*1024];   // 64 KB
  __shared__ float snv[16][17];
  int t = threadIdx.x;
  int c0 = blockIdx.x * 1024;
  int nb = blockIdx.y * 16;
  for (int idx = t; idx < 16*1024; idx += 256) {
    int d = idx >> 10, e = idx & 1023;
    int ge = c0 + e;
    wgc[idx] = (ge < KIO) ? wg[(size_t)d*KIO + ge] : 0.f;
  }
  snv[t >> 4][t & 15] = nv[(size_t)(n0 + nb + (t >> 4))*16 + (t & 15)];
  __syncthreads();
  int tx = t & 63;          // elem lane: 4 floats at tx*4 + c*256, c=0..3
  int ty = t >> 6;          // node group: 4 nodes at ty*4
  float acc[4][4][4];       // [node][chunk][q]
  #pragma unroll
  for (int p = 0; p < 4; ++p)
    #pragma unroll
    for (int c = 0; c < 4; ++c)
      #pragma unroll
      for (int q = 0; q < 4; ++q) acc[p][c][q] = 0.f;
  #pragma unroll
  for (int d = 0; d < 16; ++d) {
    float4 w[4];
    #pragma unroll
    for (int c = 0; c < 4; ++c)
      w[c] = *(const float4*)&wgc[d*1024 + c*256 + tx*4];
    float sv[4];
    #pragma unroll
    for (int p = 0; p < 4; ++p) sv[p] = snv[ty*4+p][d];   // wave-uniform broadcast
    #pragma unroll
    for (int p = 0; p < 4; ++p)
      #pragma unroll
      for (int c = 0; c < 4; ++c) {
        acc[p][c][0] += sv[p]*w[c].x;
        acc[p][c][1] += sv[p]*w[c].y;
        acc[p][c][2] += sv[p]*w[c].z;
        acc[p][c][3] += sv[p]*w[c].w;
      }
  }
  #pragma unroll
  for (int p = 0; p < 4; ++p) {
    float* dst = W + (size_t)(nb + ty*4 + p)*KIO + c0;
    #pragma unroll
    for (int c = 0; c < 4; ++c) {
      int e = c*256 + tx*4;
      if (c0 + e < KIO) *(float4*)&dst[e] = *(float4*)&acc[p][c];
    }
  }
}

// ---------------- contract v2: stream precomputed W chunk ----------------
template<int O, int ACT>   // ACT 0: sigmoid, 1: tanh
__global__ __launch_bounds__(256) void k_contract2(
    const float* __restrict__ xs, const float* __restrict__ W,
    const float* __restrict__ nv, const float* __restrict__ bg,
    float* __restrict__ outg, int n0)
{
  constexpr int G = O/64;
  __shared__ float xt[BB*II];      // [b][i]
  __shared__ float Wt[II*O];       // [i][o]
  __shared__ float snv[16];
  int n = n0 + blockIdx.x, t = threadIdx.x;
  if (t < 16) snv[t] = nv[n*16+t];
  int b0 = (t >> 4) * 4;
  int oc = (t & 15) * 4;
  float acc[4][G][4] = {};
  const float* Wn = W + (size_t)blockIdx.x*KMX*II*O;
  for (int k = 0; k < KMX; ++k) {
    __syncthreads();
    const float4* src = (const float4*)(xs + (size_t)(k*1024+n)*CC);
    for (int e = t; e < BB*II/4; e += 256) ((float4*)xt)[e] = src[e];
    const float4* wk = (const float4*)(Wn + (size_t)k*II*O);
    for (int e = t; e < II*O/4; e += 256) ((float4*)Wt)[e] = wk[e];
    __syncthreads();
    #pragma unroll 2
    for (int i = 0; i < II; ++i) {
      float xr[4];
      #pragma unroll
      for (int bb = 0; bb < 4; ++bb) xr[bb] = xt[(b0+bb)*II + i];
      #pragma unroll
      for (int g = 0; g < G; ++g) {
        float4 w4 = *(const float4*)&Wt[i*O + g*64 + oc];
        #pragma unroll
        for (int bb = 0; bb < 4; ++bb) {
          acc[bb][g][0] += xr[bb]*w4.x;
          acc[bb][g][1] += xr[bb]*w4.y;
          acc[bb][g][2] += xr[bb]*w4.z;
          acc[bb][g][3] += xr[bb]*w4.w;
        }
      }
    }
  }
  float bias[G][4];
  #pragma unroll
  for (int g = 0; g < G; ++g)
    #pragma unroll
    for (int q = 0; q < 4; ++q) {
      float bv = 0.f;
      #pragma unroll
      for (int d = 0; d < 16; ++d) bv += snv[d]*bg[d*O + g*64 + oc + q];
      bias[g][q] = bv;
    }
  #pragma unroll
  for (int bb = 0; bb < 4; ++bb) {
    float* dst = outg + (size_t)(n*BB + b0+bb)*O;
    #pragma unroll
    for (int g = 0; g < G; ++g) {
      float4 r;
      float v0 = acc[bb][g][0] + bias[g][0];
      float v1 = acc[bb][g][1] + bias[g][1];
      float v2 = acc[bb][g][2] + bias[g][2];
      float v3 = acc[bb][g][3] + bias[g][3];
      if (ACT) { r.x = tanhf(v0); r.y = tanhf(v1); r.z = tanhf(v2); r.w = tanhf(v3); }
      else {
        r.x = 1.f/(1.f+expf(-v0)); r.y = 1.f/(1.f+expf(-v1));
        r.z = 1.f/(1.f+expf(-v2)); r.w = 1.f/(1.f+expf(-v3));
      }
      *(float4*)&dst[g*64 + oc] = r;
    }
  }
}

// ---------------- contract v1 (fallback if ws too small) ----------------
template<int O, int ACT>
__global__ __launch_bounds__(256) void k_contract(
    const float* __restrict__ xs, const float* __restrict__ nv,
    const float* __restrict__ wg, const float* __restrict__ bg, float* __restrict__ outg)
{
  constexpr int G = O/64;
  __shared__ float xt[BB*II];
  __shared__ float Wt[II*O];
  __shared__ float snv[16];
  int n = blockIdx.x, t = threadIdx.x;
  if (t < 16) snv[t] = nv[n*16+t];
  int b0 = (t >> 4) * 4;
  int oc = (t & 15) * 4;
  float acc[4][G][4] = {};
  for (int k = 0; k < KMX; ++k) {
    __syncthreads();
    const float* src = xs + (size_t)(k*1024+n)*CC;
    for (int e = t; e < BB*II; e += 256) xt[e] = src[e];
    const float* wk = wg + (size_t)k*II*O;
    for (int e = t; e < II*O; e += 256) {
      float w = 0.f;
      #pragma unroll
      for (int d = 0; d < 16; ++d) w += snv[d]*wk[(size_t)d*KMX*II*O + e];
      Wt[e] = w;
    }
    __syncthreads();
    #pragma unroll 2
    for (int i = 0; i < II; ++i) {
      float xr[4];
      #pragma unroll
      for (int bb = 0; bb < 4; ++bb) xr[bb] = xt[(b0+bb)*II + i];
      #pragma unroll
      for (int g = 0; g < G; ++g) {
        float4 w4 = *(const float4*)&Wt[i*O + g*64 + oc];
        #pragma unroll
        for (int bb = 0; bb < 4; ++bb) {
          acc[bb][g][0] += xr[bb]*w4.x;
          acc[bb][g][1] += xr[bb]*w4.y;
          acc[bb][g][2] += xr[bb]*w4.z;
          acc[bb][g][3] += xr[bb]*w4.w;
        }
      }
    }
  }
  float bias[G][4];
  #pragma unroll
  for (int g = 0; g < G; ++g)
    #pragma unroll
    for (int q = 0; q < 4; ++q) {
      float bv = 0.f;
      #pragma unroll
      for (int d = 0; d < 16; ++d) bv += snv[d]*bg[d*O + g*64 + oc + q];
      bias[g][q] = bv;
    }
  #pragma unroll
  for (int bb = 0; bb < 4; ++bb) {
    float* dst = outg + (size_t)(n*BB + b0+bb)*O;
    #pragma unroll
    for (int g = 0; g < G; ++g) {
      float4 r;
      float v0 = acc[bb][g][0] + bias[g][0];
      float v1 = acc[bb][g][1] + bias[g][1];
      float v2 = acc[bb][g][2] + bias[g][2];
      float v3 = acc[bb][g][3] + bias[g][3];
      if (ACT) { r.x = tanhf(v0); r.y = tanhf(v1); r.z = tanhf(v2); r.w = tanhf(v3); }
      else {
        r.x = 1.f/(1.f+expf(-v0)); r.y = 1.f/(1.f+expf(-v1));
        r.z = 1.f/(1.f+expf(-v2)); r.w = 1.f/(1.f+expf(-v3));
      }
      *(float4*)&dst[g*64 + oc] = r;
    }
  }
}

// ---------------- final gate combine ----------------
__global__ __launch_bounds__(256) void k_out(
    const float* __restrict__ ru, const float* __restrict__ cb,
    const float* __restrict__ state, float* __restrict__ out)
{
  int idx = blockIdx.x*256 + threadIdx.x;   // over N*B*H = 4194304
  int j = idx % HH;
  int b = (idx / HH) % BB;
  int n = idx / (HH*BB);
  float u = ru[(size_t)(n*BB+b)*128 + 64 + j];
  float h = state[(size_t)b*(NN*HH) + n*HH + j];
  float c = cb[(size_t)(n*BB+b)*HH + j];
  out[(size_t)b*(NN*HH) + n*HH + j] = u*h + (1.f-u)*c;
}

extern "C" void kernel_launch(void* const* d_in, const int* in_sizes, int n_in,
                              void* d_out, int out_size, void* d_ws, size_t ws_size,
                              hipStream_t stream)
{
  const float* inputs  = (const float*)d_in[0];
  const float* state   = (const float*)d_in[1];
  const float* nv1     = (const float*)d_in[2];
  const float* nv2     = (const float*)d_in[3];
  const float* w1      = (const float*)d_in[4];
  const float* b1      = (const float*)d_in[5];
  const float* w2      = (const float*)d_in[6];
  const float* b2      = (const float*)d_in[7];
  const float* ru_wg   = (const float*)d_in[8];
  const float* ru_bg   = (const float*)d_in[9];
  const float* can_wg  = (const float*)d_in[10];
  const float* can_bg  = (const float*)d_in[11];
  const float* support0= (const float*)d_in[12];
  const float* support1= (const float*)d_in[13];
  float* out = (float*)d_out;

  float* ws = (float*)d_ws;
  float* nv       = ws;                        // 16384
  float* csr_vals = nv + 16384;                // 131072
  int*   csr_cols = (int*)(csr_vals + 131072); // 131072
  int*   csr_cnts = csr_cols + 131072;         // 2048
  __hip_bfloat16* adp_bf = (__hip_bfloat16*)(csr_cnts + 2048); // 1M bf16 = 524288 floats
  float* xs       = (float*)(csr_cnts + 2048) + 524288;        // 30277632
  float* ru       = xs + (size_t)KMX*NN*CC;    // 8388608
  float* cb       = ru + (size_t)NN*BB*128;    // 4194304
  __hip_bfloat16* XT = (__hip_bfloat16*)cb;    // alias: cb dead until last contract
  float* Wbuf     = cb + (size_t)NN*BB*64;     // chunked W

  const size_t KIO128 = (size_t)KMX*II*128;    // 59136
  size_t baseFloats = (size_t)(Wbuf - ws);
  size_t availFloats = (ws_size/4 > baseFloats) ? ws_size/4 - baseFloats : 0;
  int chunk = 0;
  if      (availFloats >= 1024*KIO128) chunk = 1024;
  else if (availFloats >=  512*KIO128) chunk = 512;
  else if (availFloats >=  256*KIO128) chunk = 256;
  else if (availFloats >=  128*KIO128) chunk = 128;
  else if (availFloats >=   64*KIO128) chunk = 64;

  k_adp_nv<<<1024, 256, 0, stream>>>(nv1, nv2, w1, b1, w2, b2, adp_bf, nv);
  k_csr<<<2048, 256, 0, stream>>>(support0, support1, csr_vals, csr_cols, csr_cnts);

  dim3 gxs(66, 16);     // k_xsplit tiles
  dim3 ggm(66, 16);     // k_gemm_mfma tiles

  // ================= diff_conv 1 (state = h) =================
  k_x0<0><<<16896, 256, 0, stream>>>(inputs, state, nullptr, xs);
  for (int s = 0; s < 2; ++s) {
    float* p1 = xs + (size_t)(1+2*s)*NN*CC;
    float* p2 = xs + (size_t)(2+2*s)*NN*CC;
    k_spmm<0><<<1024, 256, 0, stream>>>(csr_vals, csr_cols, csr_cnts, s, xs, nullptr, p1);
    k_spmm<1><<<1024, 256, 0, stream>>>(csr_vals, csr_cols, csr_cnts, s, p1, xs, p2);
  }
  {
    float* p1 = xs + (size_t)5*NN*CC;
    float* p2 = xs + (size_t)6*NN*CC;
    k_xsplit<<<gxs, 256, 0, stream>>>(xs, XT);
    k_gemm_mfma<0><<<ggm, 64, 0, stream>>>(adp_bf, XT, nullptr, p1);
    k_xsplit<<<gxs, 256, 0, stream>>>(p1, XT);
    k_gemm_mfma<1><<<ggm, 64, 0, stream>>>(adp_bf, XT, xs, p2);
  }
  if (chunk) {
    for (int n0 = 0; n0 < NN; n0 += chunk) {
      dim3 gg((KMX*II*128 + 1023)/1024, chunk/16);
      k_genw<128><<<gg, 256, 0, stream>>>(nv, ru_wg, Wbuf, n0);
      k_contract2<128,0><<<chunk, 256, 0, stream>>>(xs, Wbuf, nv, ru_bg, ru, n0);
    }
  } else {
    k_contract<128,0><<<1024, 256, 0, stream>>>(xs, nv, ru_wg, ru_bg, ru);
  }

  // ================= diff_conv 2 (state = r*h) =================
  k_x0<1><<<16896, 256, 0, stream>>>(inputs, state, ru, xs);
  for (int s = 0; s < 2; ++s) {
    float* p1 = xs + (size_t)(1+2*s)*NN*CC;
    float* p2 = xs + (size_t)(2+2*s)*NN*CC;
    k_spmm<0><<<1024, 256, 0, stream>>>(csr_vals, csr_cols, csr_cnts, s, xs, nullptr, p1);
    k_spmm<1><<<1024, 256, 0, stream>>>(csr_vals, csr_cols, csr_cnts, s, p1, xs, p2);
  }
  {
    float* p1 = xs + (size_t)5*NN*CC;
    float* p2 = xs + (size_t)6*NN*CC;
    k_xsplit<<<gxs, 256, 0, stream>>>(xs, XT);
    k_gemm_mfma<0><<<ggm, 64, 0, stream>>>(adp_bf, XT, nullptr, p1);
    k_xsplit<<<gxs, 256, 0, stream>>>(p1, XT);
    k_gemm_mfma<1><<<ggm, 64, 0, stream>>>(adp_bf, XT, xs, p2);
  }
  if (chunk) {
    for (int n0 = 0; n0 < NN; n0 += chunk) {
      dim3 gg((KMX*II*64 + 1023)/1024, chunk/16);
      k_genw<64><<<gg, 256, 0, stream>>>(nv, can_wg, Wbuf, n0);
      k_contract2<64,1><<<chunk, 256, 0, stream>>>(xs, Wbuf, nv, can_bg, cb, n0);
    }
  } else {
    k_contract<64,1><<<1024, 256, 0, stream>>>(xs, nv, can_wg, can_bg, cb);
  }

  k_out<<<16384, 256, 0, stream>>>(ru, cb, state, out);
}

// Round 7
// 1207.094 us; speedup vs baseline: 1.3007x; 1.3007x over previous
//
#include <hip/hip_runtime.h>
#include <hip/hip_bf16.h>
#include <math.h>

#define NN 1024
#define BB 64
#define DIN 2
#define HH 64
#define II 66
#define EE 16
#define KMX 7
#define CC (BB*II)   // 4224

typedef __attribute__((ext_vector_type(8))) short short8;   // 8 bf16 (4 VGPRs)
typedef __attribute__((ext_vector_type(4))) float f32x4;

// ---------------- adp softmax (bf16 out) + nv ----------------
__global__ __launch_bounds__(256) void k_adp_nv(
    const float* __restrict__ nv1, const float* __restrict__ nv2,
    const float* __restrict__ w1, const float* __restrict__ b1,
    const float* __restrict__ w2, const float* __restrict__ b2,
    __hip_bfloat16* __restrict__ adp_bf, float* __restrict__ nv)
{
  __shared__ float s_nv1[16];
  __shared__ float logits[1024];
  __shared__ float red[256];
  int n = blockIdx.x, t = threadIdx.x;
  if (t < 16) s_nv1[t] = nv1[n*16+t];
  __syncthreads();
  float lmax = -1e30f;
  for (int m = t; m < 1024; m += 256) {
    float acc = 0.f;
    const float* v2 = nv2 + m*16;
    #pragma unroll
    for (int d = 0; d < 16; ++d) acc += s_nv1[d]*v2[d];
    acc = fmaxf(acc, 0.f);
    logits[m] = acc;
    lmax = fmaxf(lmax, acc);
  }
  red[t] = lmax; __syncthreads();
  for (int s = 128; s > 0; s >>= 1) { if (t < s) red[t] = fmaxf(red[t], red[t+s]); __syncthreads(); }
  float mx = red[0]; __syncthreads();
  float lsum = 0.f;
  for (int m = t; m < 1024; m += 256) { float e = __expf(logits[m]-mx); logits[m] = e; lsum += e; }
  red[t] = lsum; __syncthreads();
  for (int s = 128; s > 0; s >>= 1) { if (t < s) red[t] += red[t+s]; __syncthreads(); }
  float inv = 1.f/red[0];
  for (int m = t; m < 1024; m += 256) adp_bf[n*1024+m] = __float2bfloat16(logits[m]*inv);
  if (t < 16) {
    float a = 0.f, c = 0.f;
    #pragma unroll
    for (int d = 0; d < 16; ++d) a += s_nv1[d]*w1[d*16+t];
    #pragma unroll
    for (int d = 0; d < 16; ++d) c += nv2[n*16+d]*w2[d*16+t];
    a = tanhf(a + b1[t]);
    c = 1.f/(1.f+expf(-(c + b2[t])));
    nv[n*16+t] = a*c;
  }
}

// ---------------- CSR build for sparse supports ----------------
__global__ __launch_bounds__(256) void k_csr(
    const float* __restrict__ s0, const float* __restrict__ s1,
    float* __restrict__ vals, int* __restrict__ cols, int* __restrict__ cnts)
{
  int row = blockIdx.x & 1023;
  int sup = blockIdx.x >> 10;
  const float* S = (sup == 0) ? s0 : s1;
  __shared__ int cnt;
  if (threadIdx.x == 0) cnt = 0;
  __syncthreads();
  int base = (sup*1024 + row)*64;
  for (int m = threadIdx.x; m < 1024; m += 256) {
    float v = S[row*1024+m];
    if (v != 0.f) {
      int idx = atomicAdd(&cnt, 1);
      if (idx < 64) { cols[base+idx] = m; vals[base+idx] = v; }
    }
  }
  __syncthreads();
  if (threadIdx.x == 0) cnts[sup*1024+row] = min(cnt, 64);
}

// ---------------- build x0 into xs slot 0, layout [n][b][i] ----------------
template<int MODE>
__global__ __launch_bounds__(256) void k_x0(
    const float* __restrict__ inputs, const float* __restrict__ state,
    const float* __restrict__ ru, float* __restrict__ xs)
{
  int idx = blockIdx.x*256 + threadIdx.x;       // over N*B*I = 4325376
  int i = idx % II;
  int b = (idx / II) % BB;
  int n = idx / (II*BB);
  float v;
  if (i < DIN) v = inputs[b*(NN*DIN) + n*DIN + i];
  else {
    v = state[b*(NN*HH) + n*HH + (i-DIN)];
    if (MODE == 1) v *= ru[(size_t)(n*BB + b)*128 + (i-DIN)];
  }
  xs[idx] = v;
}

// ---------------- sparse SpMM: Y = S@X  (or 2*S@X - X0), float4 ----------------
template<int P2>
__global__ __launch_bounds__(256) void k_spmm(
    const float* __restrict__ vals, const int* __restrict__ cols, const int* __restrict__ cnts,
    int sup, const float* __restrict__ Xsrc, const float* __restrict__ X0, float* __restrict__ Y)
{
  int n = blockIdx.x;
  __shared__ float sv[64];
  __shared__ int sc[64];
  int cnt = cnts[sup*1024+n];
  if (threadIdx.x < 64 && threadIdx.x < cnt) {
    sv[threadIdx.x] = vals[(sup*1024+n)*64 + threadIdx.x];
    sc[threadIdx.x] = cols[(sup*1024+n)*64 + threadIdx.x] * (CC/4);
  }
  __syncthreads();
  const float4* X4  = (const float4*)Xsrc;
  const float4* X04 = (const float4*)X0;
  float4* Y4 = (float4*)Y;
  for (int c = threadIdx.x; c < CC/4; c += 256) {
    float4 acc = {0.f,0.f,0.f,0.f};
    for (int j = 0; j < cnt; ++j) {
      float s = sv[j];
      float4 x = X4[sc[j] + c];
      acc.x += s*x.x; acc.y += s*x.y; acc.z += s*x.z; acc.w += s*x.w;
    }
    size_t o = (size_t)n*(CC/4) + c;
    if (P2) {
      float4 z = X04[o];
      acc.x = 2.f*acc.x - z.x; acc.y = 2.f*acc.y - z.y;
      acc.z = 2.f*acc.z - z.z; acc.w = 2.f*acc.w - z.w;
    }
    Y4[o] = acc;
  }
}

// ---------------- X [1024][4224] fp32 -> XT [4224][1024] bf16 ----------------
__global__ __launch_bounds__(256) void k_xsplit(
    const float* __restrict__ in, __hip_bfloat16* __restrict__ out)
{
  __shared__ float t[64][65];
  int cb = blockIdx.x*64, kb = blockIdx.y*64;
  int tx = threadIdx.x & 63, ty = threadIdx.x >> 6;   // 64 x 4
  for (int r = ty; r < 64; r += 4) t[r][tx] = in[(size_t)(kb+r)*CC + cb+tx];
  __syncthreads();
  int kp = threadIdx.x & 31, cr0 = threadIdx.x >> 5;  // 32 k-pairs x 8 c-rows
  for (int cr = cr0; cr < 64; cr += 8) {
    __hip_bfloat16 h0 = __float2bfloat16(t[kp*2][cr]);
    __hip_bfloat16 h1 = __float2bfloat16(t[kp*2+1][cr]);
    ushort2 u;
    u.x = *(unsigned short*)&h0;
    u.y = *(unsigned short*)&h1;
    *(ushort2*)&out[(size_t)(cb+cr)*1024 + kb + kp*2] = u;
  }
}

// ---------------- MFMA GEMM: Y[m][c] = adp[m][:]@X[:,c] (opt 2*acc - X0) ----
template<int P2>
__global__ __launch_bounds__(64) void k_gemm_mfma(
    const __hip_bfloat16* __restrict__ A, const __hip_bfloat16* __restrict__ XT,
    const float* __restrict__ X0, float* __restrict__ Y)
{
  int l = threadIdx.x;
  int c0 = blockIdx.x*64, m0 = blockIdx.y*64;
  int lr = l & 15, lg = l >> 4;          // frag row, k-group
  f32x4 acc[4][4] = {};                  // [m-frag][c-frag]
  const short* Ab  = (const short*)A;
  const short* Xb  = (const short*)XT;
  for (int k0 = 0; k0 < 1024; k0 += 32) {
    short8 af[4], bf[4];
    #pragma unroll
    for (int mf = 0; mf < 4; ++mf)
      af[mf] = *(const short8*)&Ab[(size_t)(m0 + mf*16 + lr)*1024 + k0 + lg*8];
    #pragma unroll
    for (int cf = 0; cf < 4; ++cf)
      bf[cf] = *(const short8*)&Xb[(size_t)(c0 + cf*16 + lr)*1024 + k0 + lg*8];
    #pragma unroll
    for (int mf = 0; mf < 4; ++mf)
      #pragma unroll
      for (int cf = 0; cf < 4; ++cf)
        acc[mf][cf] = __builtin_amdgcn_mfma_f32_16x16x32_bf16(af[mf], bf[cf], acc[mf][cf], 0, 0, 0);
  }
  // D map: col = lane&15 (c), row = (lane>>4)*4 + r (m)
  #pragma unroll
  for (int mf = 0; mf < 4; ++mf)
    #pragma unroll
    for (int cf = 0; cf < 4; ++cf)
      #pragma unroll
      for (int r = 0; r < 4; ++r) {
        int m = m0 + mf*16 + lg*4 + r;
        int c = c0 + cf*16 + lr;
        size_t o = (size_t)m*CC + c;
        float v = acc[mf][cf][r];
        Y[o] = P2 ? 2.f*v - X0[o] : v;
      }
}

// ---------------- W pre-gen v3: no wg LDS staging (latency-bound fix) ------
// Thread t owns elems [c0+4t, c0+4t+4) for ALL 16 nodes. wg float4s loaded
// straight from global (wave = contiguous 1KB per d, L2-resident, zero
// redundancy); nv tile (1KB) in LDS, read as wave-uniform b128 broadcasts.
// LDS 1KB -> occupancy wave-limited (~8 blocks/CU vs 2 before).
template<int O>
__global__ __launch_bounds__(256) void k_genw(
    const float* __restrict__ nv, const float* __restrict__ wg,
    float* __restrict__ W, int n0)
{
  constexpr int KIO = KMX*II*O;
  __shared__ float snv[16][16];
  int t = threadIdx.x;
  int c0 = blockIdx.x * 1024;
  int nb = blockIdx.y * 16;
  snv[t >> 4][t & 15] = nv[(size_t)(n0 + nb + (t >> 4))*16 + (t & 15)];
  int e = c0 + t*4;
  bool ok = (e < KIO);
  f32x4 w[16];
  #pragma unroll
  for (int d = 0; d < 16; ++d) {
    if (ok) w[d] = *(const f32x4*)&wg[(size_t)d*KIO + e];
    else    w[d] = f32x4{0.f,0.f,0.f,0.f};
  }
  __syncthreads();
  #pragma unroll
  for (int node = 0; node < 16; ++node) {
    f32x4 a = {0.f,0.f,0.f,0.f};
    #pragma unroll
    for (int dq = 0; dq < 4; ++dq) {
      f32x4 s4 = *(const f32x4*)&snv[node][dq*4];   // uniform addr -> broadcast
      a += s4.x * w[dq*4+0];
      a += s4.y * w[dq*4+1];
      a += s4.z * w[dq*4+2];
      a += s4.w * w[dq*4+3];
    }
    if (ok) *(f32x4*)&W[(size_t)(nb + node)*KIO + e] = a;
  }
}

// ---------------- contract v2: stream precomputed W chunk ----------------
template<int O, int ACT>   // ACT 0: sigmoid, 1: tanh
__global__ __launch_bounds__(256) void k_contract2(
    const float* __restrict__ xs, const float* __restrict__ W,
    const float* __restrict__ nv, const float* __restrict__ bg,
    float* __restrict__ outg, int n0)
{
  constexpr int G = O/64;
  __shared__ float xt[BB*II];      // [b][i]
  __shared__ float Wt[II*O];       // [i][o]
  __shared__ float snv[16];
  int n = n0 + blockIdx.x, t = threadIdx.x;
  if (t < 16) snv[t] = nv[n*16+t];
  int b0 = (t >> 4) * 4;
  int oc = (t & 15) * 4;
  float acc[4][G][4] = {};
  const float* Wn = W + (size_t)blockIdx.x*KMX*II*O;
  for (int k = 0; k < KMX; ++k) {
    __syncthreads();
    const float4* src = (const float4*)(xs + (size_t)(k*1024+n)*CC);
    for (int e = t; e < BB*II/4; e += 256) ((float4*)xt)[e] = src[e];
    const float4* wk = (const float4*)(Wn + (size_t)k*II*O);
    for (int e = t; e < II*O/4; e += 256) ((float4*)Wt)[e] = wk[e];
    __syncthreads();
    #pragma unroll 2
    for (int i = 0; i < II; ++i) {
      float xr[4];
      #pragma unroll
      for (int bb = 0; bb < 4; ++bb) xr[bb] = xt[(b0+bb)*II + i];
      #pragma unroll
      for (int g = 0; g < G; ++g) {
        float4 w4 = *(const float4*)&Wt[i*O + g*64 + oc];
        #pragma unroll
        for (int bb = 0; bb < 4; ++bb) {
          acc[bb][g][0] += xr[bb]*w4.x;
          acc[bb][g][1] += xr[bb]*w4.y;
          acc[bb][g][2] += xr[bb]*w4.z;
          acc[bb][g][3] += xr[bb]*w4.w;
        }
      }
    }
  }
  float bias[G][4];
  #pragma unroll
  for (int g = 0; g < G; ++g)
    #pragma unroll
    for (int q = 0; q < 4; ++q) {
      float bv = 0.f;
      #pragma unroll
      for (int d = 0; d < 16; ++d) bv += snv[d]*bg[d*O + g*64 + oc + q];
      bias[g][q] = bv;
    }
  #pragma unroll
  for (int bb = 0; bb < 4; ++bb) {
    float* dst = outg + (size_t)(n*BB + b0+bb)*O;
    #pragma unroll
    for (int g = 0; g < G; ++g) {
      float4 r;
      float v0 = acc[bb][g][0] + bias[g][0];
      float v1 = acc[bb][g][1] + bias[g][1];
      float v2 = acc[bb][g][2] + bias[g][2];
      float v3 = acc[bb][g][3] + bias[g][3];
      if (ACT) { r.x = tanhf(v0); r.y = tanhf(v1); r.z = tanhf(v2); r.w = tanhf(v3); }
      else {
        r.x = 1.f/(1.f+expf(-v0)); r.y = 1.f/(1.f+expf(-v1));
        r.z = 1.f/(1.f+expf(-v2)); r.w = 1.f/(1.f+expf(-v3));
      }
      *(float4*)&dst[g*64 + oc] = r;
    }
  }
}

// ---------------- contract v1 (fallback if ws too small) ----------------
template<int O, int ACT>
__global__ __launch_bounds__(256) void k_contract(
    const float* __restrict__ xs, const float* __restrict__ nv,
    const float* __restrict__ wg, const float* __restrict__ bg, float* __restrict__ outg)
{
  constexpr int G = O/64;
  __shared__ float xt[BB*II];
  __shared__ float Wt[II*O];
  __shared__ float snv[16];
  int n = blockIdx.x, t = threadIdx.x;
  if (t < 16) snv[t] = nv[n*16+t];
  int b0 = (t >> 4) * 4;
  int oc = (t & 15) * 4;
  float acc[4][G][4] = {};
  for (int k = 0; k < KMX; ++k) {
    __syncthreads();
    const float* src = xs + (size_t)(k*1024+n)*CC;
    for (int e = t; e < BB*II; e += 256) xt[e] = src[e];
    const float* wk = wg + (size_t)k*II*O;
    for (int e = t; e < II*O; e += 256) {
      float w = 0.f;
      #pragma unroll
      for (int d = 0; d < 16; ++d) w += snv[d]*wk[(size_t)d*KMX*II*O + e];
      Wt[e] = w;
    }
    __syncthreads();
    #pragma unroll 2
    for (int i = 0; i < II; ++i) {
      float xr[4];
      #pragma unroll
      for (int bb = 0; bb < 4; ++bb) xr[bb] = xt[(b0+bb)*II + i];
      #pragma unroll
      for (int g = 0; g < G; ++g) {
        float4 w4 = *(const float4*)&Wt[i*O + g*64 + oc];
        #pragma unroll
        for (int bb = 0; bb < 4; ++bb) {
          acc[bb][g][0] += xr[bb]*w4.x;
          acc[bb][g][1] += xr[bb]*w4.y;
          acc[bb][g][2] += xr[bb]*w4.z;
          acc[bb][g][3] += xr[bb]*w4.w;
        }
      }
    }
  }
  float bias[G][4];
  #pragma unroll
  for (int g = 0; g < G; ++g)
    #pragma unroll
    for (int q = 0; q < 4; ++q) {
      float bv = 0.f;
      #pragma unroll
      for (int d = 0; d < 16; ++d) bv += snv[d]*bg[d*O + g*64 + oc + q];
      bias[g][q] = bv;
    }
  #pragma unroll
  for (int bb = 0; bb < 4; ++bb) {
    float* dst = outg + (size_t)(n*BB + b0+bb)*O;
    #pragma unroll
    for (int g = 0; g < G; ++g) {
      float4 r;
      float v0 = acc[bb][g][0] + bias[g][0];
      float v1 = acc[bb][g][1] + bias[g][1];
      float v2 = acc[bb][g][2] + bias[g][2];
      float v3 = acc[bb][g][3] + bias[g][3];
      if (ACT) { r.x = tanhf(v0); r.y = tanhf(v1); r.z = tanhf(v2); r.w = tanhf(v3); }
      else {
        r.x = 1.f/(1.f+expf(-v0)); r.y = 1.f/(1.f+expf(-v1));
        r.z = 1.f/(1.f+expf(-v2)); r.w = 1.f/(1.f+expf(-v3));
      }
      *(float4*)&dst[g*64 + oc] = r;
    }
  }
}

// ---------------- final gate combine ----------------
__global__ __launch_bounds__(256) void k_out(
    const float* __restrict__ ru, const float* __restrict__ cb,
    const float* __restrict__ state, float* __restrict__ out)
{
  int idx = blockIdx.x*256 + threadIdx.x;   // over N*B*H = 4194304
  int j = idx % HH;
  int b = (idx / HH) % BB;
  int n = idx / (HH*BB);
  float u = ru[(size_t)(n*BB+b)*128 + 64 + j];
  float h = state[(size_t)b*(NN*HH) + n*HH + j];
  float c = cb[(size_t)(n*BB+b)*HH + j];
  out[(size_t)b*(NN*HH) + n*HH + j] = u*h + (1.f-u)*c;
}

extern "C" void kernel_launch(void* const* d_in, const int* in_sizes, int n_in,
                              void* d_out, int out_size, void* d_ws, size_t ws_size,
                              hipStream_t stream)
{
  const float* inputs  = (const float*)d_in[0];
  const float* state   = (const float*)d_in[1];
  const float* nv1     = (const float*)d_in[2];
  const float* nv2     = (const float*)d_in[3];
  const float* w1      = (const float*)d_in[4];
  const float* b1      = (const float*)d_in[5];
  const float* w2      = (const float*)d_in[6];
  const float* b2      = (const float*)d_in[7];
  const float* ru_wg   = (const float*)d_in[8];
  const float* ru_bg   = (const float*)d_in[9];
  const float* can_wg  = (const float*)d_in[10];
  const float* can_bg  = (const float*)d_in[11];
  const float* support0= (const float*)d_in[12];
  const float* support1= (const float*)d_in[13];
  float* out = (float*)d_out;

  float* ws = (float*)d_ws;
  float* nv       = ws;                        // 16384
  float* csr_vals = nv + 16384;                // 131072
  int*   csr_cols = (int*)(csr_vals + 131072); // 131072
  int*   csr_cnts = csr_cols + 131072;         // 2048
  __hip_bfloat16* adp_bf = (__hip_bfloat16*)(csr_cnts + 2048); // 1M bf16 = 524288 floats
  float* xs       = (float*)(csr_cnts + 2048) + 524288;        // 30277632
  float* ru       = xs + (size_t)KMX*NN*CC;    // 8388608
  float* cb       = ru + (size_t)NN*BB*128;    // 4194304
  __hip_bfloat16* XT = (__hip_bfloat16*)cb;    // alias: cb dead until last contract
  float* Wbuf     = cb + (size_t)NN*BB*64;     // chunked W

  const size_t KIO128 = (size_t)KMX*II*128;    // 59136
  size_t baseFloats = (size_t)(Wbuf - ws);
  size_t availFloats = (ws_size/4 > baseFloats) ? ws_size/4 - baseFloats : 0;
  int chunk = 0;
  if      (availFloats >= 1024*KIO128) chunk = 1024;
  else if (availFloats >=  512*KIO128) chunk = 512;
  else if (availFloats >=  256*KIO128) chunk = 256;
  else if (availFloats >=  128*KIO128) chunk = 128;
  else if (availFloats >=   64*KIO128) chunk = 64;

  k_adp_nv<<<1024, 256, 0, stream>>>(nv1, nv2, w1, b1, w2, b2, adp_bf, nv);
  k_csr<<<2048, 256, 0, stream>>>(support0, support1, csr_vals, csr_cols, csr_cnts);

  dim3 gxs(66, 16);     // k_xsplit tiles
  dim3 ggm(66, 16);     // k_gemm_mfma tiles

  // ================= diff_conv 1 (state = h) =================
  k_x0<0><<<16896, 256, 0, stream>>>(inputs, state, nullptr, xs);
  for (int s = 0; s < 2; ++s) {
    float* p1 = xs + (size_t)(1+2*s)*NN*CC;
    float* p2 = xs + (size_t)(2+2*s)*NN*CC;
    k_spmm<0><<<1024, 256, 0, stream>>>(csr_vals, csr_cols, csr_cnts, s, xs, nullptr, p1);
    k_spmm<1><<<1024, 256, 0, stream>>>(csr_vals, csr_cols, csr_cnts, s, p1, xs, p2);
  }
  {
    float* p1 = xs + (size_t)5*NN*CC;
    float* p2 = xs + (size_t)6*NN*CC;
    k_xsplit<<<gxs, 256, 0, stream>>>(xs, XT);
    k_gemm_mfma<0><<<ggm, 64, 0, stream>>>(adp_bf, XT, nullptr, p1);
    k_xsplit<<<gxs, 256, 0, stream>>>(p1, XT);
    k_gemm_mfma<1><<<ggm, 64, 0, stream>>>(adp_bf, XT, xs, p2);
  }
  if (chunk) {
    for (int n0 = 0; n0 < NN; n0 += chunk) {
      dim3 gg((KMX*II*128 + 1023)/1024, chunk/16);
      k_genw<128><<<gg, 256, 0, stream>>>(nv, ru_wg, Wbuf, n0);
      k_contract2<128,0><<<chunk, 256, 0, stream>>>(xs, Wbuf, nv, ru_bg, ru, n0);
    }
  } else {
    k_contract<128,0><<<1024, 256, 0, stream>>>(xs, nv, ru_wg, ru_bg, ru);
  }

  // ================= diff_conv 2 (state = r*h) =================
  k_x0<1><<<16896, 256, 0, stream>>>(inputs, state, ru, xs);
  for (int s = 0; s < 2; ++s) {
    float* p1 = xs + (size_t)(1+2*s)*NN*CC;
    float* p2 = xs + (size_t)(2+2*s)*NN*CC;
    k_spmm<0><<<1024, 256, 0, stream>>>(csr_vals, csr_cols, csr_cnts, s, xs, nullptr, p1);
    k_spmm<1><<<1024, 256, 0, stream>>>(csr_vals, csr_cols, csr_cnts, s, p1, xs, p2);
  }
  {
    float* p1 = xs + (size_t)5*NN*CC;
    float* p2 = xs + (size_t)6*NN*CC;
    k_xsplit<<<gxs, 256, 0, stream>>>(xs, XT);
    k_gemm_mfma<0><<<ggm, 64, 0, stream>>>(adp_bf, XT, nullptr, p1);
    k_xsplit<<<gxs, 256, 0, stream>>>(p1, XT);
    k_gemm_mfma<1><<<ggm, 64, 0, stream>>>(adp_bf, XT, xs, p2);
  }
  if (chunk) {
    for (int n0 = 0; n0 < NN; n0 += chunk) {
      dim3 gg((KMX*II*64 + 1023)/1024, chunk/16);
      k_genw<64><<<gg, 256, 0, stream>>>(nv, can_wg, Wbuf, n0);
      k_contract2<64,1><<<chunk, 256, 0, stream>>>(xs, Wbuf, nv, can_bg, cb, n0);
    }
  } else {
    k_contract<64,1><<<1024, 256, 0, stream>>>(xs, nv, can_wg, can_bg, cb);
  }

  k_out<<<16384, 256, 0, stream>>>(ru, cb, state, out);
}